// Round 9
// baseline (125.994 us; speedup 1.0000x reference)
//
#include <hip/hip_runtime.h>
#include <math.h>

// Problem constants
#define BATCH 2
#define SEQ   2048
#define DIM   1024
#define RANK  256
#define HEADS 16
#define HS    16
#define DH    64
#define MROWS 4096

#define QSCALE 0.36067376f   // 0.25 * log2(e), folded into normalized q

typedef __attribute__((ext_vector_type(8)))  short    short8;   // 8 bf16
typedef __attribute__((ext_vector_type(4)))  float    f32x4;
typedef __attribute__((ext_vector_type(16))) float    f32x16;
typedef __attribute__((ext_vector_type(2)))  unsigned uint2v;

#define GPTR const __attribute__((address_space(1))) unsigned int*
#define LPTR __attribute__((address_space(3))) unsigned int*

__device__ __forceinline__ unsigned short f2bf(float f) {
    union { float f; unsigned u; } v; v.f = f;
    return (unsigned short)((v.u + 0x7FFFu + ((v.u >> 16) & 1u)) >> 16);  // RNE
}
__device__ __forceinline__ float bf2f(unsigned short h) {
    union { unsigned u; float f; } v; v.u = ((unsigned)h) << 16;
    return v.f;
}

// ---------------- fused f32 -> bf16 convert for x, Wqk, Wv ----------------
#define XQ   1048576
#define WQKQ 131072
#define WVQ  262144
__global__ __launch_bounds__(256) void conv3(const float* __restrict__ x,
                                             const float* __restrict__ wqk,
                                             const float* __restrict__ wv,
                                             unsigned short* __restrict__ xb,
                                             unsigned short* __restrict__ wcat)
{
    const int i = blockIdx.x * 256 + threadIdx.x;
    const float* src; unsigned short* dst; int j;
    if (i < XQ)              { src = x;   dst = xb;   j = i; }
    else if (i < XQ + WQKQ)  { src = wqk; dst = wcat; j = i - XQ; }
    else                     { src = wv;  dst = wcat + (size_t)4 * WQKQ; j = i - XQ - WQKQ; }
    float4 v = ((const float4*)src)[j];
    ushort4 o; o.x = f2bf(v.x); o.y = f2bf(v.y); o.z = f2bf(v.z); o.w = f2bf(v.w);
    ((ushort4*)dst)[j] = o;
}

// ---------------- MFMA GEMM, 128x64 tile, BK=64, XOR-swizzled LDS ----------------
// 16 MFMA per barrier-pair (m97 ratio). XCD-chunked flat grid (768 = 8*96).
__global__ __launch_bounds__(256) void gemm_mfma(const unsigned short* __restrict__ A,
                                                 const unsigned short* __restrict__ W,
                                                 unsigned short* __restrict__ qkb,
                                                 unsigned short* __restrict__ vt)
{
    __shared__ __align__(16) unsigned short Alds[128 * 64];  // 16 KB
    __shared__ __align__(16) unsigned short Blds[64 * 64];   //  8 KB

    const int tid = threadIdx.x;
    const int w = tid >> 6, lane = tid & 63;
    const int lr = lane & 15, lg = lane >> 4;
    const int wm = w >> 1, wn = w & 1;

    const int Lf = blockIdx.x;                 // 768 blocks
    const int wg = (Lf & 7) * 96 + (Lf >> 3);  // bijective XCD chunking
    const int bm = (wg & 31) * 128;
    const int bn = (wg >> 5) * 64;

    const int rs = lane >> 3, cs = lane & 7;   // staging: 8 rows x 8 slots per gload

    f32x4 acc[4][2] = {};

    for (int k0 = 0; k0 < 1024; k0 += 64) {
        __syncthreads();
        #pragma unroll
        for (int i = 0; i < 4; ++i) {          // A: 128 rows, 8 rows per gload
            const int r = w * 32 + i * 8 + rs;
            __builtin_amdgcn_global_load_lds(
                (GPTR)&A[(size_t)(bm + r) * 1024 + k0 + 8 * (cs ^ (r & 7))],
                (LPTR)&Alds[(w * 32 + i * 8) * 64], 16, 0, 0);
        }
        #pragma unroll
        for (int i = 0; i < 2; ++i) {          // B: 64 rows
            const int r = w * 16 + i * 8 + rs;
            __builtin_amdgcn_global_load_lds(
                (GPTR)&W[(size_t)(bn + r) * 1024 + k0 + 8 * (cs ^ (r & 7))],
                (LPTR)&Blds[(w * 16 + i * 8) * 64], 16, 0, 0);
        }
        __syncthreads();

        #pragma unroll
        for (int kk = 0; kk < 2; ++kk) {
            short8 af[4], bfr[2];
            #pragma unroll
            for (int mi = 0; mi < 4; ++mi) {
                const int row = wm * 64 + mi * 16 + lr;
                af[mi] = *(const short8*)&Alds[row * 64 + 8 * ((kk * 4 + lg) ^ (row & 7))];
            }
            #pragma unroll
            for (int ni = 0; ni < 2; ++ni) {
                const int row = wn * 32 + ni * 16 + lr;
                bfr[ni] = *(const short8*)&Blds[row * 64 + 8 * ((kk * 4 + lg) ^ (row & 7))];
            }
            #pragma unroll
            for (int mi = 0; mi < 4; ++mi)
                #pragma unroll
                for (int ni = 0; ni < 2; ++ni)
                    acc[mi][ni] = __builtin_amdgcn_mfma_f32_16x16x32_bf16(af[mi], bfr[ni], acc[mi][ni], 0, 0, 0);
        }
    }

    if (bn < 512) {
        #pragma unroll
        for (int mi = 0; mi < 4; ++mi) {
            const int rbase = bm + wm * 64 + mi * 16 + lg * 4;
            #pragma unroll
            for (int ni = 0; ni < 2; ++ni) {
                const int col = bn + wn * 32 + ni * 16 + lr;
                #pragma unroll
                for (int r = 0; r < 4; ++r)
                    qkb[(size_t)(rbase + r) * 512 + col] = f2bf(acc[mi][ni][r]);
            }
        }
    } else {
        const int nb = bn - 512;
        #pragma unroll
        for (int mi = 0; mi < 4; ++mi) {
            const int m = bm + wm * 64 + mi * 16 + lg * 4;
            const int bb = m >> 11, ms = m & 2047;
            #pragma unroll
            for (int ni = 0; ni < 2; ++ni) {
                const int d = nb + wn * 32 + ni * 16 + lr;
                ushort4 pk;
                pk.x = f2bf(acc[mi][ni][0]); pk.y = f2bf(acc[mi][ni][1]);
                pk.z = f2bf(acc[mi][ni][2]); pk.w = f2bf(acc[mi][ni][3]);
                *(ushort4*)&vt[((size_t)bb * DIM + d) * SEQ + ms] = pk;
            }
        }
    }
}

// ---------------- Full-rank L2 normalize; q pre-scaled by QSCALE ----------------
__global__ __launch_bounds__(256) void l2norm_split(const unsigned short* __restrict__ qkb,
                                                    unsigned short* __restrict__ qn,
                                                    unsigned short* __restrict__ kn)
{
    const int row = blockIdx.x;
    const int t = threadIdx.x;
    const unsigned short* p = qkb + (size_t)row * 512;
    float q = bf2f(p[t]);
    float k = bf2f(p[t + 256]);
    float sq = q * q, sk = k * k;
    #pragma unroll
    for (int off = 32; off > 0; off >>= 1) {
        sq += __shfl_down(sq, off);
        sk += __shfl_down(sk, off);
    }
    __shared__ float sh[8];
    const int wid = t >> 6;
    if ((t & 63) == 0) { sh[wid * 2] = sq; sh[wid * 2 + 1] = sk; }
    __syncthreads();
    sq = sh[0] + sh[2] + sh[4] + sh[6];
    sk = sh[1] + sh[3] + sh[5] + sh[7];
    const float rq = QSCALE / fmaxf(sqrtf(sq), 1e-6f);
    const float rk = 1.0f   / fmaxf(sqrtf(sk), 1e-6f);
    qn[(size_t)row * 256 + t] = f2bf(q * rq);
    kn[(size_t)row * 256 + t] = f2bf(k * rk);
}

// ---------------- attn: band-pair blocks, 4 kh-waves (4 waves/SIMD) ----------------
// Block = q-band pair {63-j, j} (32 rows each; total tiles 17-18, uniform).
// 4 waves each own 32 keys of every 128-key tile -> 1 QK mfma + 16 exp2 per seg.
// Grid 1024 = 4 blocks/CU = 16 waves/CU. XCD-pinned (L&31=bh). V dbuf LDS,
// &15 XOR swizzle; K global->reg w/ prefetch. No-max softmax (exp2 direct).

template<bool MASK>
__device__ __forceinline__ void tile_bp(const unsigned short* Vs, int kb, int kh,
                                        int l31, int hi, int qg,
                                        const short8 ak, const short8 bq,
                                        f32x16 o[2], float& lp)
{
    const f32x16 z = {};
    const f32x16 s = __builtin_amdgcn_mfma_f32_32x32x16_bf16(ak, bq, z, 0, 0, 0);

    float p[16];
    #pragma unroll
    for (int r = 0; r < 16; ++r) {
        float e = __builtin_exp2f(s[r]);
        if (MASK) {
            const int kl = kb + (r & 3) + 8 * (r >> 2) + 4 * hi;
            e = (kl > qg) ? 0.0f : e;
        }
        p[r] = e;
        lp += e;
    }

    short8 pa[2];
    #pragma unroll
    for (int g = 0; g < 2; ++g) {
        const int jj = 2 * g;
        unsigned a0, a1, b0, b1;
        asm("v_cvt_pk_bf16_f32 %0, %1, %2" : "=v"(a0) : "v"(p[4*jj]),     "v"(p[4*jj + 1]));
        asm("v_cvt_pk_bf16_f32 %0, %1, %2" : "=v"(b0) : "v"(p[4*jj + 2]), "v"(p[4*jj + 3]));
        asm("v_cvt_pk_bf16_f32 %0, %1, %2" : "=v"(a1) : "v"(p[4*jj + 4]), "v"(p[4*jj + 5]));
        asm("v_cvt_pk_bf16_f32 %0, %1, %2" : "=v"(b1) : "v"(p[4*jj + 6]), "v"(p[4*jj + 7]));
        const uint2v r0 = __builtin_amdgcn_permlane32_swap(a0, a1, false, false);
        const uint2v r1 = __builtin_amdgcn_permlane32_swap(b0, b1, false, false);
        union { short8 s; unsigned u[4]; } pu;
        pu.u[0] = r0[0]; pu.u[1] = r1[0]; pu.u[2] = r0[1]; pu.u[3] = r1[1];
        pa[g] = pu.s;
    }

    #pragma unroll
    for (int g = 0; g < 2; ++g)
        #pragma unroll
        for (int half = 0; half < 2; ++half) {
            const int row = half * 32 + l31;
            const int slot = (4 * kh + 2 * g + hi) ^ (row & 15);
            const short8 bv = *(const short8*)&Vs[row * 128 + 8 * slot];
            o[half] = __builtin_amdgcn_mfma_f32_32x32x16_bf16(pa[g], bv, o[half], 0, 0, 0);
        }
}

__device__ __forceinline__ void seg_dispatch(const unsigned short* Vs, int kb, int kh,
                                             int l31, int hi, int band, int qg, bool last,
                                             const short8 ak, const short8 bq,
                                             f32x16 o[2], float& lp)
{
    if (!last) {
        tile_bp<false>(Vs, kb, kh, l31, hi, qg, ak, bq, o, lp);       // fully unmasked
    } else if (kb <= band * 32 + 31) {
        if (kb + 31 <= band * 32)
            tile_bp<false>(Vs, kb, kh, l31, hi, qg, ak, bq, o, lp);
        else
            tile_bp<true>(Vs, kb, kh, l31, hi, qg, ak, bq, o, lp);
    }   // else: window above all q rows -> skip
}

__global__ __launch_bounds__(256, 4) void attn_bp(const unsigned short* __restrict__ qn,
                                                  const unsigned short* __restrict__ kn,
                                                  const unsigned short* __restrict__ vt,
                                                  float* __restrict__ out)
{
    const int L = blockIdx.x;            // 1024; L%8 == bh%8 -> XCD-pinned
    const int bh = L & 31;
    const int j  = L >> 5;               // 0..31 -> band pair {63-j, j}
    const int h = bh & 15, b = bh >> 4;

    const int tid = threadIdx.x, kh = tid >> 6, lane = tid & 63;
    const int l31 = lane & 31, hi = lane >> 5;

    const int band0 = 63 - j, band1 = j;
    const int nt0 = (band0 >> 2) + 1;    // 9..16
    const int nt1 = (band1 >> 2) + 1;    // 1..8 (< nt0)
    const int qg0 = band0 * 32 + l31, qg1 = band1 * 32 + l31;

    __shared__ __align__(16) unsigned char smem[32768 + 2048];  // V dbuf 2x16K | Ls 2K

    const short8 bq0 = *(const short8*)&qn[((size_t)b * SEQ + qg0) * RANK + h * HS + 8 * hi];
    const short8 bq1 = *(const short8*)&qn[((size_t)b * SEQ + qg1) * RANK + h * HS + 8 * hi];

    f32x16 o0[2] = {}, o1[2] = {};
    float lp0 = 0.0f, lp1 = 0.0f;

    // K A-frag: wave kh's 32-key window; one short8 per tile, prefetched
    const unsigned short* kpbase = kn + ((size_t)b * SEQ + 32 * kh + l31) * RANK + h * HS + 8 * hi;
    short8 ak = *(const short8*)kpbase;

    const int vsub  = lane >> 4;         // 0..3
    const int vslot = lane & 15;

#define STAGEV(kt_, buf_) do {                                                                    \
        const int k0_ = (kt_) * 128;                                                              \
        _Pragma("unroll")                                                                         \
        for (int i = 0; i < 4; ++i) {                                                             \
            const int dh = kh * 16 + i * 4 + vsub;                                                \
            const int so = 8 * (vslot ^ (dh & 15));                                               \
            __builtin_amdgcn_global_load_lds(                                                     \
                (GPTR)&vt[((size_t)b * DIM + h * DH + dh) * SEQ + k0_ + so],                      \
                (LPTR)(smem + (buf_) * 16384 + (kh * 16 + i * 4) * 256), 16, 0, 0);               \
        }                                                                                         \
    } while (0)

    STAGEV(0, 0);
    __syncthreads();

    #pragma unroll 1
    for (int kt = 0; kt < nt0; ++kt) {
        const bool more = (kt + 1 < nt0);
        if (more) STAGEV(kt + 1, (kt + 1) & 1);
        short8 an = ak;
        if (more) an = *(const short8*)(kpbase + (size_t)(kt + 1) * 128 * RANK);

        const unsigned short* Vs = (const unsigned short*)(smem + (kt & 1) * 16384);
        const int kb = kt * 128 + 32 * kh;

        __builtin_amdgcn_s_setprio(1);
        seg_dispatch(Vs, kb, kh, l31, hi, band0, qg0, kt == nt0 - 1, ak, bq0, o0, lp0);
        if (kt < nt1)
            seg_dispatch(Vs, kb, kh, l31, hi, band1, qg1, kt == nt1 - 1, ak, bq1, o1, lp1);
        __builtin_amdgcn_s_setprio(0);

        ak = an;
        __syncthreads();
    }
#undef STAGEV

    // ---- epilogue: 4-way kh merge per segment via LDS tree ----
    lp0 += __shfl_xor(lp0, 32);          // combine hi halves (per q=l31)
    lp1 += __shfl_xor(lp1, 32);

    float* Os = (float*)smem;            // [2 slots][2 seg][32 q][64 lane] = 32 KB
    float* Ls = (float*)(smem + 32768);  // [2 seg][4 kh][64 lane] = 2 KB

    __syncthreads();                     // V staging dead
    Ls[(0 * 4 + kh) * 64 + lane] = lp0;
    Ls[(1 * 4 + kh) * 64 + lane] = lp1;
    if (kh >= 2) {
        const int slot = kh - 2;
        #pragma unroll
        for (int half = 0; half < 2; ++half)
            #pragma unroll
            for (int r = 0; r < 16; ++r) {
                const int q = (r & 3) + 8 * (r >> 2) + 4 * hi;
                Os[((slot * 2 + 0) * 32 + q) * 64 + half * 32 + l31] = o0[half][r];
                Os[((slot * 2 + 1) * 32 + q) * 64 + half * 32 + l31] = o1[half][r];
            }
    }
    __syncthreads();
    if (kh < 2) {
        #pragma unroll
        for (int half = 0; half < 2; ++half)
            #pragma unroll
            for (int r = 0; r < 16; ++r) {
                const int q = (r & 3) + 8 * (r >> 2) + 4 * hi;
                o0[half][r] += Os[((kh * 2 + 0) * 32 + q) * 64 + half * 32 + l31];
                o1[half][r] += Os[((kh * 2 + 1) * 32 + q) * 64 + half * 32 + l31];
            }
    }
    __syncthreads();
    if (kh == 1) {
        #pragma unroll
        for (int half = 0; half < 2; ++half)
            #pragma unroll
            for (int r = 0; r < 16; ++r) {
                const int q = (r & 3) + 8 * (r >> 2) + 4 * hi;
                Os[((0 * 2 + 0) * 32 + q) * 64 + half * 32 + l31] = o0[half][r];
                Os[((0 * 2 + 1) * 32 + q) * 64 + half * 32 + l31] = o1[half][r];
            }
    }
    __syncthreads();
    if (kh == 0) {
        float lt0 = Ls[(0 * 4 + 0) * 64 + lane] + Ls[(0 * 4 + 1) * 64 + lane]
                  + Ls[(0 * 4 + 2) * 64 + lane] + Ls[(0 * 4 + 3) * 64 + lane];
        float lt1 = Ls[(1 * 4 + 0) * 64 + lane] + Ls[(1 * 4 + 1) * 64 + lane]
                  + Ls[(1 * 4 + 2) * 64 + lane] + Ls[(1 * 4 + 3) * 64 + lane];
        const float inv0 = 1.0f / fmaxf(lt0, 1e-6f);
        const float inv1 = 1.0f / fmaxf(lt1, 1e-6f);
        #pragma unroll
        for (int r = 0; r < 16; ++r) {
            const int q = (r & 3) + 8 * (r >> 2) + 4 * hi;
            const float iv0 = __shfl(inv0, q);
            const float iv1 = __shfl(inv1, q);
            #pragma unroll
            for (int half = 0; half < 2; ++half) {
                const float v0 = (o0[half][r] + Os[((0 * 2 + 0) * 32 + q) * 64 + half * 32 + l31]) * iv0;
                const float v1 = (o1[half][r] + Os[((0 * 2 + 1) * 32 + q) * 64 + half * 32 + l31]) * iv1;
                __builtin_nontemporal_store(v0,
                    &out[((size_t)b * SEQ + band0 * 32 + q) * DIM + h * DH + half * 32 + l31]);
                __builtin_nontemporal_store(v1,
                    &out[((size_t)b * SEQ + band1 * 32 + q) * DIM + h * DH + half * 32 + l31]);
            }
        }
    }
}

extern "C" void kernel_launch(void* const* d_in, const int* in_sizes, int n_in,
                              void* d_out, int out_size, void* d_ws, size_t ws_size,
                              hipStream_t stream)
{
    const float* x   = (const float*)d_in[0];
    // d_in[1] = mask (causal, analytic)
    const float* Wqk = (const float*)d_in[2];
    const float* Wv  = (const float*)d_in[3];
    float* out = (float*)d_out;

    // workspace: xb 8MB | qkb 4MB | vt 8MB | wcat 3MB ; qn/kn overlay xb after GEMM
    unsigned short* xb   = (unsigned short*)d_ws;
    unsigned short* qkb  = xb  + (size_t)MROWS * DIM;
    unsigned short* vt   = qkb + (size_t)MROWS * 512;
    unsigned short* wcat = vt  + (size_t)BATCH * DIM * SEQ;
    unsigned short* qn = xb;
    unsigned short* kn = xb + (size_t)MROWS * RANK;

    conv3<<<5632, 256, 0, stream>>>(x, Wqk, Wv, xb, wcat);
    gemm_mfma<<<768, 256, 0, stream>>>(xb, wcat, qkb, vt);
    l2norm_split<<<MROWS, 256, 0, stream>>>(qkb, qn, kn);
    attn_bp<<<1024, 256, 0, stream>>>(qn, kn, vt, out);
}

// Round 10
// 79.293 us; speedup vs baseline: 1.5890x; 1.5890x over previous
//
#include <hip/hip_runtime.h>
#include <math.h>

// Problem constants
#define BATCH 2
#define SEQ   2048
#define DIM   1024
#define RANK  256
#define HEADS 16
#define HS    16
#define DH    64
#define MROWS 4096

#define QSCALE 0.36067376f   // 0.25 * log2(e), folded into normalized q

typedef __attribute__((ext_vector_type(8)))  short    short8;   // 8 bf16
typedef __attribute__((ext_vector_type(4)))  float    f32x4;
typedef __attribute__((ext_vector_type(16))) float    f32x16;
typedef __attribute__((ext_vector_type(2)))  unsigned uint2v;

#define GPTR const __attribute__((address_space(1))) unsigned int*
#define LPTR __attribute__((address_space(3))) unsigned int*

__device__ __forceinline__ unsigned short f2bf(float f) {
    union { float f; unsigned u; } v; v.f = f;
    return (unsigned short)((v.u + 0x7FFFu + ((v.u >> 16) & 1u)) >> 16);  // RNE
}
__device__ __forceinline__ float bf2f(unsigned short h) {
    union { unsigned u; float f; } v; v.u = ((unsigned)h) << 16;
    return v.f;
}

// ---------------- fused f32 -> bf16 convert for x, Wqk, Wv ----------------
#define XQ   1048576
#define WQKQ 131072
#define WVQ  262144
__global__ __launch_bounds__(256) void conv3(const float* __restrict__ x,
                                             const float* __restrict__ wqk,
                                             const float* __restrict__ wv,
                                             unsigned short* __restrict__ xb,
                                             unsigned short* __restrict__ wcat)
{
    const int i = blockIdx.x * 256 + threadIdx.x;
    const float* src; unsigned short* dst; int j;
    if (i < XQ)              { src = x;   dst = xb;   j = i; }
    else if (i < XQ + WQKQ)  { src = wqk; dst = wcat; j = i - XQ; }
    else                     { src = wv;  dst = wcat + (size_t)4 * WQKQ; j = i - XQ - WQKQ; }
    float4 v = ((const float4*)src)[j];
    ushort4 o; o.x = f2bf(v.x); o.y = f2bf(v.y); o.z = f2bf(v.z); o.w = f2bf(v.w);
    ((ushort4*)dst)[j] = o;
}

// ---------------- MFMA GEMM, 128x64 tile, BK=64, XOR-swizzled LDS ----------------
__global__ __launch_bounds__(256) void gemm_mfma(const unsigned short* __restrict__ A,
                                                 const unsigned short* __restrict__ W,
                                                 unsigned short* __restrict__ qkb,
                                                 unsigned short* __restrict__ vt)
{
    __shared__ __align__(16) unsigned short Alds[128 * 64];  // 16 KB
    __shared__ __align__(16) unsigned short Blds[64 * 64];   //  8 KB

    const int tid = threadIdx.x;
    const int w = tid >> 6, lane = tid & 63;
    const int lr = lane & 15, lg = lane >> 4;
    const int wm = w >> 1, wn = w & 1;

    const int Lf = blockIdx.x;                 // 768 blocks
    const int wg = (Lf & 7) * 96 + (Lf >> 3);  // bijective XCD chunking
    const int bm = (wg & 31) * 128;
    const int bn = (wg >> 5) * 64;

    const int rs = lane >> 3, cs = lane & 7;

    f32x4 acc[4][2] = {};

    for (int k0 = 0; k0 < 1024; k0 += 64) {
        __syncthreads();
        #pragma unroll
        for (int i = 0; i < 4; ++i) {
            const int r = w * 32 + i * 8 + rs;
            __builtin_amdgcn_global_load_lds(
                (GPTR)&A[(size_t)(bm + r) * 1024 + k0 + 8 * (cs ^ (r & 7))],
                (LPTR)&Alds[(w * 32 + i * 8) * 64], 16, 0, 0);
        }
        #pragma unroll
        for (int i = 0; i < 2; ++i) {
            const int r = w * 16 + i * 8 + rs;
            __builtin_amdgcn_global_load_lds(
                (GPTR)&W[(size_t)(bn + r) * 1024 + k0 + 8 * (cs ^ (r & 7))],
                (LPTR)&Blds[(w * 16 + i * 8) * 64], 16, 0, 0);
        }
        __syncthreads();

        #pragma unroll
        for (int kk = 0; kk < 2; ++kk) {
            short8 af[4], bfr[2];
            #pragma unroll
            for (int mi = 0; mi < 4; ++mi) {
                const int row = wm * 64 + mi * 16 + lr;
                af[mi] = *(const short8*)&Alds[row * 64 + 8 * ((kk * 4 + lg) ^ (row & 7))];
            }
            #pragma unroll
            for (int ni = 0; ni < 2; ++ni) {
                const int row = wn * 32 + ni * 16 + lr;
                bfr[ni] = *(const short8*)&Blds[row * 64 + 8 * ((kk * 4 + lg) ^ (row & 7))];
            }
            #pragma unroll
            for (int mi = 0; mi < 4; ++mi)
                #pragma unroll
                for (int ni = 0; ni < 2; ++ni)
                    acc[mi][ni] = __builtin_amdgcn_mfma_f32_16x16x32_bf16(af[mi], bfr[ni], acc[mi][ni], 0, 0, 0);
        }
    }

    if (bn < 512) {
        #pragma unroll
        for (int mi = 0; mi < 4; ++mi) {
            const int rbase = bm + wm * 64 + mi * 16 + lg * 4;
            #pragma unroll
            for (int ni = 0; ni < 2; ++ni) {
                const int col = bn + wn * 32 + ni * 16 + lr;
                #pragma unroll
                for (int r = 0; r < 4; ++r)
                    qkb[(size_t)(rbase + r) * 512 + col] = f2bf(acc[mi][ni][r]);
            }
        }
    } else {
        const int nb = bn - 512;
        #pragma unroll
        for (int mi = 0; mi < 4; ++mi) {
            const int m = bm + wm * 64 + mi * 16 + lg * 4;
            const int bb = m >> 11, ms = m & 2047;
            #pragma unroll
            for (int ni = 0; ni < 2; ++ni) {
                const int d = nb + wn * 32 + ni * 16 + lr;
                ushort4 pk;
                pk.x = f2bf(acc[mi][ni][0]); pk.y = f2bf(acc[mi][ni][1]);
                pk.z = f2bf(acc[mi][ni][2]); pk.w = f2bf(acc[mi][ni][3]);
                *(ushort4*)&vt[((size_t)bb * DIM + d) * SEQ + ms] = pk;
            }
        }
    }
}

// ---------------- Full-rank L2 normalize; q pre-scaled by QSCALE ----------------
__global__ __launch_bounds__(256) void l2norm_split(const unsigned short* __restrict__ qkb,
                                                    unsigned short* __restrict__ qn,
                                                    unsigned short* __restrict__ kn)
{
    const int row = blockIdx.x;
    const int t = threadIdx.x;
    const unsigned short* p = qkb + (size_t)row * 512;
    float q = bf2f(p[t]);
    float k = bf2f(p[t + 256]);
    float sq = q * q, sk = k * k;
    #pragma unroll
    for (int off = 32; off > 0; off >>= 1) {
        sq += __shfl_down(sq, off);
        sk += __shfl_down(sk, off);
    }
    __shared__ float sh[8];
    const int wid = t >> 6;
    if ((t & 63) == 0) { sh[wid * 2] = sq; sh[wid * 2 + 1] = sk; }
    __syncthreads();
    sq = sh[0] + sh[2] + sh[4] + sh[6];
    sk = sh[1] + sh[3] + sh[5] + sh[7];
    const float rq = QSCALE / fmaxf(sqrtf(sq), 1e-6f);
    const float rk = 1.0f   / fmaxf(sqrtf(sk), 1e-6f);
    qn[(size_t)row * 256 + t] = f2bf(q * rq);
    kn[(size_t)row * 256 + t] = f2bf(k * rk);
}

// ---------------- attn: barrier-free band-pair, direct-global V ----------------
// Block = band pair {63-j, j} x 4 kh-waves (each owns 32 keys of a 128-key
// tile). NO LDS staging, NO k-loop barriers: PV B-frags load straight from
// vt[b][d][n] (16B/lane contiguous; (g,hi) pairs fill 64B sectors; slice is
// L2-resident via XCD pinning L&31=bh). K global->reg one-tile prefetch.
// launch_bounds(256,3): ~168 VGPR cap, NO spills (R9 lesson). Epilogue: 4-way
// kh merge in LDS (only post-loop barriers).

__device__ __forceinline__ void seg_pv(bool mask, const f32x16& s, int kb, int hi, int qg,
                                       const short8 vb[2][2], f32x16 o[2], float& lp)
{
    float p[16];
    if (mask) {
        #pragma unroll
        for (int r = 0; r < 16; ++r) {
            float e = __builtin_exp2f(s[r]);
            const int kl = kb + (r & 3) + 8 * (r >> 2) + 4 * hi;
            e = (kl > qg) ? 0.0f : e;
            p[r] = e; lp += e;
        }
    } else {
        #pragma unroll
        for (int r = 0; r < 16; ++r) {
            const float e = __builtin_exp2f(s[r]);
            p[r] = e; lp += e;
        }
    }

    short8 pa[2];
    #pragma unroll
    for (int g = 0; g < 2; ++g) {
        const int jj = 2 * g;
        unsigned a0, a1, b0, b1;
        asm("v_cvt_pk_bf16_f32 %0, %1, %2" : "=v"(a0) : "v"(p[4*jj]),     "v"(p[4*jj + 1]));
        asm("v_cvt_pk_bf16_f32 %0, %1, %2" : "=v"(b0) : "v"(p[4*jj + 2]), "v"(p[4*jj + 3]));
        asm("v_cvt_pk_bf16_f32 %0, %1, %2" : "=v"(a1) : "v"(p[4*jj + 4]), "v"(p[4*jj + 5]));
        asm("v_cvt_pk_bf16_f32 %0, %1, %2" : "=v"(b1) : "v"(p[4*jj + 6]), "v"(p[4*jj + 7]));
        const uint2v r0 = __builtin_amdgcn_permlane32_swap(a0, a1, false, false);
        const uint2v r1 = __builtin_amdgcn_permlane32_swap(b0, b1, false, false);
        union { short8 s; unsigned u[4]; } pu;
        pu.u[0] = r0[0]; pu.u[1] = r1[0]; pu.u[2] = r0[1]; pu.u[3] = r1[1];
        pa[g] = pu.s;
    }

    #pragma unroll
    for (int g = 0; g < 2; ++g)
        #pragma unroll
        for (int half = 0; half < 2; ++half)
            o[half] = __builtin_amdgcn_mfma_f32_32x32x16_bf16(pa[g], vb[g][half], o[half], 0, 0, 0);
}

__global__ __launch_bounds__(256, 3) void attn_bf(const unsigned short* __restrict__ qn,
                                                  const unsigned short* __restrict__ kn,
                                                  const unsigned short* __restrict__ vt,
                                                  float* __restrict__ out)
{
    const int L = blockIdx.x;            // 1024; L%8 == bh%8 -> XCD-pinned
    const int bh = L & 31;
    const int j  = L >> 5;               // 0..31 -> band pair {63-j, j}
    const int h = bh & 15, b = bh >> 4;

    const int tid = threadIdx.x, kh = tid >> 6, lane = tid & 63;
    const int l31 = lane & 31, hi = lane >> 5;

    const int band0 = 63 - j, band1 = j;
    const int nt0 = (band0 >> 2) + 1;    // 9..16 (128-key tiles)
    const int nt1 = (band1 >> 2) + 1;    // 1..8 (< nt0)
    const int qg0 = band0 * 32 + l31, qg1 = band1 * 32 + l31;
    const int qtop0 = band0 * 32 + 31, qtop1 = band1 * 32 + 31;

    __shared__ __align__(16) unsigned char smem[34816];  // Os 32K | Ls 2K (epilogue only)

    const short8 bq0 = *(const short8*)&qn[((size_t)b * SEQ + qg0) * RANK + h * HS + 8 * hi];
    const short8 bq1 = *(const short8*)&qn[((size_t)b * SEQ + qg1) * RANK + h * HS + 8 * hi];

    f32x16 o0[2] = {}, o1[2] = {};
    float lp0 = 0.0f, lp1 = 0.0f;
    const f32x16 z = {};

    // K A-frag: wave kh's 32-key window of each 128-key tile
    const unsigned short* kpbase = kn + ((size_t)b * SEQ + 32 * kh + l31) * RANK + h * HS + 8 * hi;
    short8 ak = *(const short8*)kpbase;

    // V B-frag base: row = dh (half*32 + l31), col = key
    const unsigned short* vbase = vt + ((size_t)b * DIM + h * DH + l31) * SEQ + 32 * kh + 16 * 0 + 8 * hi;

    #pragma unroll 1
    for (int kt = 0; kt < nt0; ++kt) {
        const int kb = kt * 128 + 32 * kh;
        short8 an = ak;
        if (kt + 1 < nt0) an = *(const short8*)(kpbase + (size_t)(kt + 1) * 128 * RANK);

        if (kb <= qtop0) {
            // V fragments straight from global (L2-resident slice)
            short8 vb[2][2];
            #pragma unroll
            for (int g = 0; g < 2; ++g)
                #pragma unroll
                for (int half = 0; half < 2; ++half)
                    vb[g][half] = *(const short8*)(vbase + (size_t)(half * 32) * SEQ + kt * 128 + 16 * g);

            const f32x16 s0 = __builtin_amdgcn_mfma_f32_32x32x16_bf16(ak, bq0, z, 0, 0, 0);
            seg_pv(kt == nt0 - 1 && kb + 31 > qtop0 - 31, s0, kb, hi, qg0, vb, o0, lp0);

            if (kt < nt1 && kb <= qtop1) {
                const f32x16 s1 = __builtin_amdgcn_mfma_f32_32x32x16_bf16(ak, bq1, z, 0, 0, 0);
                seg_pv(kt == nt1 - 1 && kb + 31 > qtop1 - 31, s1, kb, hi, qg1, vb, o1, lp1);
            }
        }
        ak = an;
    }

    // ---- epilogue: 4-way kh merge per segment via LDS tree ----
    lp0 += __shfl_xor(lp0, 32);
    lp1 += __shfl_xor(lp1, 32);

    float* Os = (float*)smem;            // [2 slots][2 seg][32 q][64 lane] = 32 KB
    float* Ls = (float*)(smem + 32768);  // [2 seg][4 kh][64 lane] = 2 KB

    __syncthreads();
    Ls[(0 * 4 + kh) * 64 + lane] = lp0;
    Ls[(1 * 4 + kh) * 64 + lane] = lp1;
    if (kh >= 2) {
        const int slot = kh - 2;
        #pragma unroll
        for (int half = 0; half < 2; ++half)
            #pragma unroll
            for (int r = 0; r < 16; ++r) {
                const int q = (r & 3) + 8 * (r >> 2) + 4 * hi;
                Os[((slot * 2 + 0) * 32 + q) * 64 + half * 32 + l31] = o0[half][r];
                Os[((slot * 2 + 1) * 32 + q) * 64 + half * 32 + l31] = o1[half][r];
            }
    }
    __syncthreads();
    if (kh < 2) {
        #pragma unroll
        for (int half = 0; half < 2; ++half)
            #pragma unroll
            for (int r = 0; r < 16; ++r) {
                const int q = (r & 3) + 8 * (r >> 2) + 4 * hi;
                o0[half][r] += Os[((kh * 2 + 0) * 32 + q) * 64 + half * 32 + l31];
                o1[half][r] += Os[((kh * 2 + 1) * 32 + q) * 64 + half * 32 + l31];
            }
    }
    __syncthreads();
    if (kh == 1) {
        #pragma unroll
        for (int half = 0; half < 2; ++half)
            #pragma unroll
            for (int r = 0; r < 16; ++r) {
                const int q = (r & 3) + 8 * (r >> 2) + 4 * hi;
                Os[((0 * 2 + 0) * 32 + q) * 64 + half * 32 + l31] = o0[half][r];
                Os[((0 * 2 + 1) * 32 + q) * 64 + half * 32 + l31] = o1[half][r];
            }
    }
    __syncthreads();
    if (kh == 0) {
        float lt0 = Ls[(0 * 4 + 0) * 64 + lane] + Ls[(0 * 4 + 1) * 64 + lane]
                  + Ls[(0 * 4 + 2) * 64 + lane] + Ls[(0 * 4 + 3) * 64 + lane];
        float lt1 = Ls[(1 * 4 + 0) * 64 + lane] + Ls[(1 * 4 + 1) * 64 + lane]
                  + Ls[(1 * 4 + 2) * 64 + lane] + Ls[(1 * 4 + 3) * 64 + lane];
        const float inv0 = 1.0f / fmaxf(lt0, 1e-6f);
        const float inv1 = 1.0f / fmaxf(lt1, 1e-6f);
        #pragma unroll
        for (int r = 0; r < 16; ++r) {
            const int q = (r & 3) + 8 * (r >> 2) + 4 * hi;
            const float iv0 = __shfl(inv0, q);
            const float iv1 = __shfl(inv1, q);
            #pragma unroll
            for (int half = 0; half < 2; ++half) {
                const float v0 = (o0[half][r] + Os[((0 * 2 + 0) * 32 + q) * 64 + half * 32 + l31]) * iv0;
                const float v1 = (o1[half][r] + Os[((0 * 2 + 1) * 32 + q) * 64 + half * 32 + l31]) * iv1;
                __builtin_nontemporal_store(v0,
                    &out[((size_t)b * SEQ + band0 * 32 + q) * DIM + h * DH + half * 32 + l31]);
                __builtin_nontemporal_store(v1,
                    &out[((size_t)b * SEQ + band1 * 32 + q) * DIM + h * DH + half * 32 + l31]);
            }
        }
    }
}

extern "C" void kernel_launch(void* const* d_in, const int* in_sizes, int n_in,
                              void* d_out, int out_size, void* d_ws, size_t ws_size,
                              hipStream_t stream)
{
    const float* x   = (const float*)d_in[0];
    // d_in[1] = mask (causal, analytic)
    const float* Wqk = (const float*)d_in[2];
    const float* Wv  = (const float*)d_in[3];
    float* out = (float*)d_out;

    // workspace: xb 8MB | qkb 4MB | vt 8MB | wcat 3MB ; qn/kn overlay xb after GEMM
    unsigned short* xb   = (unsigned short*)d_ws;
    unsigned short* qkb  = xb  + (size_t)MROWS * DIM;
    unsigned short* vt   = qkb + (size_t)MROWS * 512;
    unsigned short* wcat = vt  + (size_t)BATCH * DIM * SEQ;
    unsigned short* qn = xb;
    unsigned short* kn = xb + (size_t)MROWS * RANK;

    conv3<<<5632, 256, 0, stream>>>(x, Wqk, Wv, xb, wcat);
    gemm_mfma<<<768, 256, 0, stream>>>(xb, wcat, qkb, vt);
    l2norm_split<<<MROWS, 256, 0, stream>>>(qkb, qn, kn);
    attn_bf<<<1024, 256, 0, stream>>>(qn, kn, vt, out);
}

// Round 11
// 70.564 us; speedup vs baseline: 1.7855x; 1.1237x over previous
//
#include <hip/hip_runtime.h>
#include <math.h>

// Problem constants
#define BATCH 2
#define SEQ   2048
#define DIM   1024
#define RANK  256
#define HEADS 16
#define HS    16
#define DH    64
#define MROWS 4096

#define QSCALE 0.36067376f   // 0.25 * log2(e), folded into normalized q

typedef __attribute__((ext_vector_type(8)))  short    short8;   // 8 bf16
typedef __attribute__((ext_vector_type(4)))  float    f32x4;
typedef __attribute__((ext_vector_type(16))) float    f32x16;
typedef __attribute__((ext_vector_type(2)))  unsigned uint2v;

#define GPTR const __attribute__((address_space(1))) unsigned int*
#define LPTR __attribute__((address_space(3))) unsigned int*

__device__ __forceinline__ unsigned short f2bf(float f) {
    union { float f; unsigned u; } v; v.f = f;
    return (unsigned short)((v.u + 0x7FFFu + ((v.u >> 16) & 1u)) >> 16);  // RNE
}
__device__ __forceinline__ float bf2f(unsigned short h) {
    union { unsigned u; float f; } v; v.u = ((unsigned)h) << 16;
    return v.f;
}

// ---------------- fused f32 -> bf16 convert for x, Wqk, Wv ----------------
#define XQ   1048576
#define WQKQ 131072
#define WVQ  262144
__global__ __launch_bounds__(256) void conv3(const float* __restrict__ x,
                                             const float* __restrict__ wqk,
                                             const float* __restrict__ wv,
                                             unsigned short* __restrict__ xb,
                                             unsigned short* __restrict__ wcat)
{
    const int i = blockIdx.x * 256 + threadIdx.x;
    const float* src; unsigned short* dst; int j;
    if (i < XQ)              { src = x;   dst = xb;   j = i; }
    else if (i < XQ + WQKQ)  { src = wqk; dst = wcat; j = i - XQ; }
    else                     { src = wv;  dst = wcat + (size_t)4 * WQKQ; j = i - XQ - WQKQ; }
    float4 v = ((const float4*)src)[j];
    ushort4 o; o.x = f2bf(v.x); o.y = f2bf(v.y); o.z = f2bf(v.z); o.w = f2bf(v.w);
    ((ushort4*)dst)[j] = o;
}

// ---------------- MFMA GEMM, 128x64 tile, BK=64, XOR-swizzled LDS ----------------
__global__ __launch_bounds__(256) void gemm_mfma(const unsigned short* __restrict__ A,
                                                 const unsigned short* __restrict__ W,
                                                 unsigned short* __restrict__ qkb,
                                                 unsigned short* __restrict__ vt)
{
    __shared__ __align__(16) unsigned short Alds[128 * 64];  // 16 KB
    __shared__ __align__(16) unsigned short Blds[64 * 64];   //  8 KB

    const int tid = threadIdx.x;
    const int w = tid >> 6, lane = tid & 63;
    const int lr = lane & 15, lg = lane >> 4;
    const int wm = w >> 1, wn = w & 1;

    const int Lf = blockIdx.x;                 // 768 blocks
    const int wg = (Lf & 7) * 96 + (Lf >> 3);  // bijective XCD chunking
    const int bm = (wg & 31) * 128;
    const int bn = (wg >> 5) * 64;

    const int rs = lane >> 3, cs = lane & 7;

    f32x4 acc[4][2] = {};

    for (int k0 = 0; k0 < 1024; k0 += 64) {
        __syncthreads();
        #pragma unroll
        for (int i = 0; i < 4; ++i) {
            const int r = w * 32 + i * 8 + rs;
            __builtin_amdgcn_global_load_lds(
                (GPTR)&A[(size_t)(bm + r) * 1024 + k0 + 8 * (cs ^ (r & 7))],
                (LPTR)&Alds[(w * 32 + i * 8) * 64], 16, 0, 0);
        }
        #pragma unroll
        for (int i = 0; i < 2; ++i) {
            const int r = w * 16 + i * 8 + rs;
            __builtin_amdgcn_global_load_lds(
                (GPTR)&W[(size_t)(bn + r) * 1024 + k0 + 8 * (cs ^ (r & 7))],
                (LPTR)&Blds[(w * 16 + i * 8) * 64], 16, 0, 0);
        }
        __syncthreads();

        #pragma unroll
        for (int kk = 0; kk < 2; ++kk) {
            short8 af[4], bfr[2];
            #pragma unroll
            for (int mi = 0; mi < 4; ++mi) {
                const int row = wm * 64 + mi * 16 + lr;
                af[mi] = *(const short8*)&Alds[row * 64 + 8 * ((kk * 4 + lg) ^ (row & 7))];
            }
            #pragma unroll
            for (int ni = 0; ni < 2; ++ni) {
                const int row = wn * 32 + ni * 16 + lr;
                bfr[ni] = *(const short8*)&Blds[row * 64 + 8 * ((kk * 4 + lg) ^ (row & 7))];
            }
            #pragma unroll
            for (int mi = 0; mi < 4; ++mi)
                #pragma unroll
                for (int ni = 0; ni < 2; ++ni)
                    acc[mi][ni] = __builtin_amdgcn_mfma_f32_16x16x32_bf16(af[mi], bfr[ni], acc[mi][ni], 0, 0, 0);
        }
    }

    if (bn < 512) {
        #pragma unroll
        for (int mi = 0; mi < 4; ++mi) {
            const int rbase = bm + wm * 64 + mi * 16 + lg * 4;
            #pragma unroll
            for (int ni = 0; ni < 2; ++ni) {
                const int col = bn + wn * 32 + ni * 16 + lr;
                #pragma unroll
                for (int r = 0; r < 4; ++r)
                    qkb[(size_t)(rbase + r) * 512 + col] = f2bf(acc[mi][ni][r]);
            }
        }
    } else {
        const int nb = bn - 512;
        #pragma unroll
        for (int mi = 0; mi < 4; ++mi) {
            const int m = bm + wm * 64 + mi * 16 + lg * 4;
            const int bb = m >> 11, ms = m & 2047;
            #pragma unroll
            for (int ni = 0; ni < 2; ++ni) {
                const int d = nb + wn * 32 + ni * 16 + lr;
                ushort4 pk;
                pk.x = f2bf(acc[mi][ni][0]); pk.y = f2bf(acc[mi][ni][1]);
                pk.z = f2bf(acc[mi][ni][2]); pk.w = f2bf(acc[mi][ni][3]);
                *(ushort4*)&vt[((size_t)bb * DIM + d) * SEQ + ms] = pk;
            }
        }
    }
}

// ---------------- L2 normalize; outputs HEAD-MAJOR qn/kn [bh][n][16] ----------------
// Head-major makes attention K/Q loads fully coalesced (32B/row contiguous).
__global__ __launch_bounds__(256) void l2norm_split(const unsigned short* __restrict__ qkb,
                                                    unsigned short* __restrict__ qn,
                                                    unsigned short* __restrict__ kn)
{
    const int row = blockIdx.x;
    const int t = threadIdx.x;
    const unsigned short* p = qkb + (size_t)row * 512;
    float q = bf2f(p[t]);
    float k = bf2f(p[t + 256]);
    float sq = q * q, sk = k * k;
    #pragma unroll
    for (int off = 32; off > 0; off >>= 1) {
        sq += __shfl_down(sq, off);
        sk += __shfl_down(sk, off);
    }
    __shared__ float sh[8];
    const int wid = t >> 6;
    if ((t & 63) == 0) { sh[wid * 2] = sq; sh[wid * 2 + 1] = sk; }
    __syncthreads();
    sq = sh[0] + sh[2] + sh[4] + sh[6];
    sk = sh[1] + sh[3] + sh[5] + sh[7];
    const float rq = QSCALE / fmaxf(sqrtf(sq), 1e-6f);
    const float rk = 1.0f   / fmaxf(sqrtf(sk), 1e-6f);

    const int b = row >> 11, n = row & 2047;
    const int head = t >> 4, hs = t & 15;
    const size_t o = (((size_t)b * HEADS + head) * SEQ + n) * 16 + hs;
    qn[o] = f2bf(q * rq);
    kn[o] = f2bf(k * rk);
}

// ---------------- attn: paired q-tiles, coalesced K, counted-vmcnt V dbuf ----------------
// 512 uniform blocks (pair {31-p, p}, 17-18 tiles each), XCD-pinned (L&31=bh).
// 4 waves = 2 qh x 2 kh. V staged coalesced via gload_lds dbuf; the per-iter
// sync is raw s_barrier + s_waitcnt vmcnt(6) -- next tile's 6 loads (4 V-stage
// + 2 K-reg) stay in flight across the barrier (T3/T4: never drain to 0).
// K loads are CONTIGUOUS 2KB/wave thanks to head-major kn. No-max softmax.

template<bool MASK>
__device__ __forceinline__ void segpv(const f32x16& s0, const f32x16& s1, int kb, int hi,
                                      int qg, const short8 vb[4][2], f32x16 o[2], float& lp)
{
    float p0[16], p1[16];
    #pragma unroll
    for (int r = 0; r < 16; ++r) {
        float e0 = __builtin_exp2f(s0[r]);
        float e1 = __builtin_exp2f(s1[r]);
        if (MASK) {
            const int kl = kb + (r & 3) + 8 * (r >> 2) + 4 * hi;
            e0 = (kl > qg) ? 0.0f : e0;
            e1 = (kl + 32 > qg) ? 0.0f : e1;
        }
        p0[r] = e0; p1[r] = e1;
        lp += e0 + e1;
    }

    short8 pa[4];
    #pragma unroll
    for (int g = 0; g < 4; ++g) {
        const float* pc = (g < 2) ? p0 : p1;
        const int jj = 2 * (g & 1);
        unsigned a0, a1, b0, b1;
        asm("v_cvt_pk_bf16_f32 %0, %1, %2" : "=v"(a0) : "v"(pc[4*jj]),     "v"(pc[4*jj + 1]));
        asm("v_cvt_pk_bf16_f32 %0, %1, %2" : "=v"(b0) : "v"(pc[4*jj + 2]), "v"(pc[4*jj + 3]));
        asm("v_cvt_pk_bf16_f32 %0, %1, %2" : "=v"(a1) : "v"(pc[4*jj + 4]), "v"(pc[4*jj + 5]));
        asm("v_cvt_pk_bf16_f32 %0, %1, %2" : "=v"(b1) : "v"(pc[4*jj + 6]), "v"(pc[4*jj + 7]));
        const uint2v r0 = __builtin_amdgcn_permlane32_swap(a0, a1, false, false);
        const uint2v r1 = __builtin_amdgcn_permlane32_swap(b0, b1, false, false);
        union { short8 s; unsigned u[4]; } pu;
        pu.u[0] = r0[0]; pu.u[1] = r1[0]; pu.u[2] = r0[1]; pu.u[3] = r1[1];
        pa[g] = pu.s;
    }

    #pragma unroll
    for (int g = 0; g < 4; ++g)
        #pragma unroll
        for (int half = 0; half < 2; ++half)
            o[half] = __builtin_amdgcn_mfma_f32_32x32x16_bf16(pa[g], vb[g][half], o[half], 0, 0, 0);
}

__global__ __launch_bounds__(256, 2) void attn_v2(const unsigned short* __restrict__ qn,
                                                  const unsigned short* __restrict__ kn,
                                                  const unsigned short* __restrict__ vt,
                                                  float* __restrict__ out)
{
    const int L = blockIdx.x;            // 512; L%8 == bh%8 -> XCD-pinned
    const int bh = L & 31;
    const int p  = L >> 5;               // 0..15 -> q-tile pair {31-p, p}
    const int h = bh & 15, b = bh >> 4;

    const int tid = threadIdx.x, w = tid >> 6, lane = tid & 63;
    const int qh = w >> 1, kh = w & 1;
    const int l31 = lane & 31, hi = lane >> 5;

    const int qt0 = 31 - p, qt1 = p;
    const int nt0 = (qt0 >> 1) + 1;      // 9..16 tiles of 128 keys
    const int nt1 = (qt1 >> 1) + 1;      // 1..8 (< nt0)
    const int qband0 = qt0 * 64 + qh * 32, qband1 = qt1 * 64 + qh * 32;
    const int qg0 = qband0 + l31, qg1 = qband1 + l31;

    // V dbuf 2x16KB; epilogue overlay Os0|Os1|Ls0|Ls1
    __shared__ __align__(16) unsigned char smem[33792];

    const unsigned short* qbh = qn + (size_t)bh * SEQ * 16;
    const unsigned short* kbh = kn + (size_t)bh * SEQ * 16;

    const short8 bq0 = *(const short8*)&qbh[qg0 * 16 + 8 * hi];
    const short8 bq1 = *(const short8*)&qbh[qg1 * 16 + 8 * hi];

    f32x16 o0[2] = {}, o1[2] = {};
    float lp0 = 0.0f, lp1 = 0.0f;
    const f32x16 z = {};

    // K window (wave kh): rows 64kh+l31, +32 of each tile. Coalesced 32B rows.
    const unsigned short* kwin = kbh + (64 * kh + l31) * 16 + 8 * hi;
    short8 ak0 = *(const short8*)(kwin);
    short8 ak1 = *(const short8*)(kwin + 32 * 16);

    const int vsub = lane >> 4, vslot = lane & 15;

#define STAGEV(kt_, buf_) do {                                                                    \
        const int k0_ = (kt_) * 128;                                                              \
        _Pragma("unroll")                                                                         \
        for (int i = 0; i < 4; ++i) {                                                             \
            const int dh = w * 16 + i * 4 + vsub;                                                 \
            const int so = 8 * (vslot ^ (dh & 7));                                                \
            __builtin_amdgcn_global_load_lds(                                                     \
                (GPTR)&vt[((size_t)b * DIM + h * DH + dh) * SEQ + k0_ + so],                      \
                (LPTR)(smem + (buf_) * 16384 + (w * 4 + i) * 1024), 16, 0, 0);                    \
        }                                                                                         \
    } while (0)

    STAGEV(0, 0);

    #pragma unroll 1
    for (int kt = 0; kt < nt0; ++kt) {
        short8 an0 = ak0, an1 = ak1;
        if (kt + 1 < nt0) {
            STAGEV(kt + 1, (kt + 1) & 1);
            an0 = *(const short8*)(kwin + (size_t)(kt + 1) * 128 * 16);
            an1 = *(const short8*)(kwin + (size_t)(kt + 1) * 128 * 16 + 32 * 16);
            asm volatile("s_waitcnt vmcnt(6)" ::: "memory");   // drain tile kt only
        } else {
            asm volatile("s_waitcnt vmcnt(0)" ::: "memory");
        }
        __builtin_amdgcn_sched_barrier(0);
        __builtin_amdgcn_s_barrier();        // all waves' stage(kt) visible

        const unsigned short* Vs = (const unsigned short*)(smem + (kt & 1) * 16384);
        const int kb = kt * 128 + 64 * kh;

        // shared V fragments (read once, feed both segments)
        short8 vb[4][2];
        #pragma unroll
        for (int g = 0; g < 4; ++g)
            #pragma unroll
            for (int half = 0; half < 2; ++half) {
                const int row = half * 32 + l31;
                const int slot = (8 * kh + 2 * g + hi) ^ (row & 7);
                vb[g][half] = *(const short8*)&Vs[row * 128 + 8 * slot];
            }

        __builtin_amdgcn_s_setprio(1);
        // ---- segment 0 (heavy) ----
        if (kt < nt0 - 1) {
            const f32x16 s0 = __builtin_amdgcn_mfma_f32_32x32x16_bf16(ak0, bq0, z, 0, 0, 0);
            const f32x16 s1 = __builtin_amdgcn_mfma_f32_32x32x16_bf16(ak1, bq0, z, 0, 0, 0);
            segpv<false>(s0, s1, kb, hi, qg0, vb, o0, lp0);
        } else if (kb <= qband0 + 31) {
            const f32x16 s0 = __builtin_amdgcn_mfma_f32_32x32x16_bf16(ak0, bq0, z, 0, 0, 0);
            const f32x16 s1 = __builtin_amdgcn_mfma_f32_32x32x16_bf16(ak1, bq0, z, 0, 0, 0);
            if (kb + 63 <= qband0) segpv<false>(s0, s1, kb, hi, qg0, vb, o0, lp0);
            else                   segpv<true >(s0, s1, kb, hi, qg0, vb, o0, lp0);
        }
        // ---- segment 1 (light, prefix of seg0's range) ----
        if (kt < nt1) {
            const f32x16 s0 = __builtin_amdgcn_mfma_f32_32x32x16_bf16(ak0, bq1, z, 0, 0, 0);
            const f32x16 s1 = __builtin_amdgcn_mfma_f32_32x32x16_bf16(ak1, bq1, z, 0, 0, 0);
            if (kt < nt1 - 1) {
                segpv<false>(s0, s1, kb, hi, qg1, vb, o1, lp1);
            } else if (kb <= qband1 + 31) {
                if (kb + 63 <= qband1) segpv<false>(s0, s1, kb, hi, qg1, vb, o1, lp1);
                else                   segpv<true >(s0, s1, kb, hi, qg1, vb, o1, lp1);
            }
        }
        __builtin_amdgcn_s_setprio(0);

        ak0 = an0; ak1 = an1;
        __builtin_amdgcn_s_barrier();        // all waves done reading buf kt
    }
#undef STAGEV

    // ---- epilogue: merge kh partials for both segments, normalize, store ----
    __syncthreads();                         // V dbuf dead; reuse smem
    float* Os0 = (float*)smem;               // [2 bands][32 q][64 lane]
    float* Os1 = (float*)(smem + 16384);
    float* Ls0 = (float*)(smem + 32768);     // [2 bands][64 lane]
    float* Ls1 = (float*)(smem + 33280);

    if (kh == 1) {
        #pragma unroll
        for (int half = 0; half < 2; ++half)
            #pragma unroll
            for (int r = 0; r < 16; ++r) {
                const int q = (r & 3) + 8 * (r >> 2) + 4 * hi;
                Os0[(qh * 32 + q) * 64 + half * 32 + l31] = o0[half][r];
                Os1[(qh * 32 + q) * 64 + half * 32 + l31] = o1[half][r];
            }
        Ls0[qh * 64 + lane] = lp0;
        Ls1[qh * 64 + lane] = lp1;
    }
    __syncthreads();
    if (kh == 0) {
        float lt0 = lp0 + Ls0[qh * 64 + lane];
        float lt1 = lp1 + Ls1[qh * 64 + lane];
        lt0 += __shfl_xor(lt0, 32);
        lt1 += __shfl_xor(lt1, 32);
        const float inv0 = 1.0f / fmaxf(lt0, 1e-6f);
        const float inv1 = 1.0f / fmaxf(lt1, 1e-6f);
        #pragma unroll
        for (int r = 0; r < 16; ++r) {
            const int q = (r & 3) + 8 * (r >> 2) + 4 * hi;
            const float iv0 = __shfl(inv0, q);
            const float iv1 = __shfl(inv1, q);
            #pragma unroll
            for (int half = 0; half < 2; ++half) {
                const float v0 = (o0[half][r] + Os0[(qh * 32 + q) * 64 + half * 32 + l31]) * iv0;
                const float v1 = (o1[half][r] + Os1[(qh * 32 + q) * 64 + half * 32 + l31]) * iv1;
                __builtin_nontemporal_store(v0,
                    &out[((size_t)b * SEQ + qband0 + q) * DIM + h * DH + half * 32 + l31]);
                __builtin_nontemporal_store(v1,
                    &out[((size_t)b * SEQ + qband1 + q) * DIM + h * DH + half * 32 + l31]);
            }
        }
    }
}

extern "C" void kernel_launch(void* const* d_in, const int* in_sizes, int n_in,
                              void* d_out, int out_size, void* d_ws, size_t ws_size,
                              hipStream_t stream)
{
    const float* x   = (const float*)d_in[0];
    // d_in[1] = mask (causal, analytic)
    const float* Wqk = (const float*)d_in[2];
    const float* Wv  = (const float*)d_in[3];
    float* out = (float*)d_out;

    // workspace: xb 8MB | qkb 4MB | vt 8MB | wcat 3MB ; qn/kn (2MB each, head-major)
    // overlay xb after the GEMM (xb dead by then)
    unsigned short* xb   = (unsigned short*)d_ws;
    unsigned short* qkb  = xb  + (size_t)MROWS * DIM;
    unsigned short* vt   = qkb + (size_t)MROWS * 512;
    unsigned short* wcat = vt  + (size_t)BATCH * DIM * SEQ;
    unsigned short* qn = xb;                               // [32 bh][2048][16]
    unsigned short* kn = xb + (size_t)32 * SEQ * 16;

    conv3<<<5632, 256, 0, stream>>>(x, Wqk, Wv, xb, wcat);
    gemm_mfma<<<768, 256, 0, stream>>>(xb, wcat, qkb, vt);
    l2norm_split<<<MROWS, 256, 0, stream>>>(qkb, qn, kn);
    attn_v2<<<512, 256, 0, stream>>>(qn, kn, vt, out);
}

// Round 12
// 68.743 us; speedup vs baseline: 1.8328x; 1.0265x over previous
//
#include <hip/hip_runtime.h>
#include <math.h>

// Problem constants
#define BATCH 2
#define SEQ   2048
#define DIM   1024
#define RANK  256
#define HEADS 16
#define HS    16
#define DH    64
#define MROWS 4096

#define QSCALE 0.36067376f   // 0.25 * log2(e), folded into normalized q

typedef __attribute__((ext_vector_type(8)))  short    short8;   // 8 bf16
typedef __attribute__((ext_vector_type(4)))  float    f32x4;
typedef __attribute__((ext_vector_type(16))) float    f32x16;
typedef __attribute__((ext_vector_type(2)))  unsigned uint2v;

#define GPTR const __attribute__((address_space(1))) unsigned int*
#define LPTR __attribute__((address_space(3))) unsigned int*

__device__ __forceinline__ unsigned short f2bf(float f) {
    union { float f; unsigned u; } v; v.f = f;
    return (unsigned short)((v.u + 0x7FFFu + ((v.u >> 16) & 1u)) >> 16);  // RNE
}
__device__ __forceinline__ float bf2f(unsigned short h) {
    union { unsigned u; float f; } v; v.u = ((unsigned)h) << 16;
    return v.f;
}

// ---------------- fused f32 -> bf16 convert for x, Wqk, Wv ----------------
#define XQ   1048576
#define WQKQ 131072
#define WVQ  262144
__global__ __launch_bounds__(256) void conv3(const float* __restrict__ x,
                                             const float* __restrict__ wqk,
                                             const float* __restrict__ wv,
                                             unsigned short* __restrict__ xb,
                                             unsigned short* __restrict__ wcat)
{
    const int i = blockIdx.x * 256 + threadIdx.x;
    const float* src; unsigned short* dst; int j;
    if (i < XQ)              { src = x;   dst = xb;   j = i; }
    else if (i < XQ + WQKQ)  { src = wqk; dst = wcat; j = i - XQ; }
    else                     { src = wv;  dst = wcat + (size_t)4 * WQKQ; j = i - XQ - WQKQ; }
    float4 v = ((const float4*)src)[j];
    ushort4 o; o.x = f2bf(v.x); o.y = f2bf(v.y); o.z = f2bf(v.z); o.w = f2bf(v.w);
    ((ushort4*)dst)[j] = o;
}

// ---------------- MFMA GEMM: 128x64 tile, BK=64, DBUF LDS + counted vmcnt ----------------
// Next K-tile's 6 gloads stay in flight across the barrier (vmcnt(6), T3/T4).
// 48 KB LDS -> 3 blocks/CU. XCD-chunked flat grid (768 = 8*96).
__global__ __launch_bounds__(256, 3) void gemm_mfma(const unsigned short* __restrict__ A,
                                                    const unsigned short* __restrict__ W,
                                                    unsigned short* __restrict__ qkb,
                                                    unsigned short* __restrict__ vt)
{
    __shared__ __align__(16) unsigned short Alds[2][128 * 64];  // 32 KB
    __shared__ __align__(16) unsigned short Blds[2][64 * 64];   // 16 KB

    const int tid = threadIdx.x;
    const int w = tid >> 6, lane = tid & 63;
    const int lr = lane & 15, lg = lane >> 4;
    const int wm = w >> 1, wn = w & 1;

    const int Lf = blockIdx.x;                 // 768 blocks
    const int wg = (Lf & 7) * 96 + (Lf >> 3);  // bijective XCD chunking
    const int bm = (wg & 31) * 128;
    const int bn = (wg >> 5) * 64;

    const int rs = lane >> 3, cs = lane & 7;

    f32x4 acc[4][2] = {};

#define STAGEG(kt_, buf_) do {                                                        \
        const int k0_ = (kt_) * 64;                                                   \
        _Pragma("unroll")                                                             \
        for (int i = 0; i < 4; ++i) {                                                 \
            const int r = w * 32 + i * 8 + rs;                                        \
            __builtin_amdgcn_global_load_lds(                                         \
                (GPTR)&A[(size_t)(bm + r) * 1024 + k0_ + 8 * (cs ^ (r & 7))],         \
                (LPTR)&Alds[buf_][(w * 32 + i * 8) * 64], 16, 0, 0);                  \
        }                                                                             \
        _Pragma("unroll")                                                             \
        for (int i = 0; i < 2; ++i) {                                                 \
            const int r = w * 16 + i * 8 + rs;                                        \
            __builtin_amdgcn_global_load_lds(                                         \
                (GPTR)&W[(size_t)(bn + r) * 1024 + k0_ + 8 * (cs ^ (r & 7))],         \
                (LPTR)&Blds[buf_][(w * 16 + i * 8) * 64], 16, 0, 0);                  \
        }                                                                             \
    } while (0)

    STAGEG(0, 0);

    #pragma unroll 1
    for (int kt = 0; kt < 16; ++kt) {
        if (kt + 1 < 16) {
            STAGEG(kt + 1, (kt + 1) & 1);
            asm volatile("s_waitcnt vmcnt(6)" ::: "memory");   // drain tile kt only
        } else {
            asm volatile("s_waitcnt vmcnt(0)" ::: "memory");
        }
        __builtin_amdgcn_sched_barrier(0);
        __builtin_amdgcn_s_barrier();

        const int buf = kt & 1;
        #pragma unroll
        for (int kk = 0; kk < 2; ++kk) {
            short8 af[4], bfr[2];
            #pragma unroll
            for (int mi = 0; mi < 4; ++mi) {
                const int row = wm * 64 + mi * 16 + lr;
                af[mi] = *(const short8*)&Alds[buf][row * 64 + 8 * ((kk * 4 + lg) ^ (row & 7))];
            }
            #pragma unroll
            for (int ni = 0; ni < 2; ++ni) {
                const int row = wn * 32 + ni * 16 + lr;
                bfr[ni] = *(const short8*)&Blds[buf][row * 64 + 8 * ((kk * 4 + lg) ^ (row & 7))];
            }
            #pragma unroll
            for (int mi = 0; mi < 4; ++mi)
                #pragma unroll
                for (int ni = 0; ni < 2; ++ni)
                    acc[mi][ni] = __builtin_amdgcn_mfma_f32_16x16x32_bf16(af[mi], bfr[ni], acc[mi][ni], 0, 0, 0);
        }
        __builtin_amdgcn_s_barrier();   // all waves done with buf before restage
    }
#undef STAGEG

    if (bn < 512) {
        #pragma unroll
        for (int mi = 0; mi < 4; ++mi) {
            const int rbase = bm + wm * 64 + mi * 16 + lg * 4;
            #pragma unroll
            for (int ni = 0; ni < 2; ++ni) {
                const int col = bn + wn * 32 + ni * 16 + lr;
                #pragma unroll
                for (int r = 0; r < 4; ++r)
                    qkb[(size_t)(rbase + r) * 512 + col] = f2bf(acc[mi][ni][r]);
            }
        }
    } else {
        const int nb = bn - 512;
        #pragma unroll
        for (int mi = 0; mi < 4; ++mi) {
            const int m = bm + wm * 64 + mi * 16 + lg * 4;
            const int bb = m >> 11, ms = m & 2047;
            #pragma unroll
            for (int ni = 0; ni < 2; ++ni) {
                const int d = nb + wn * 32 + ni * 16 + lr;
                ushort4 pk;
                pk.x = f2bf(acc[mi][ni][0]); pk.y = f2bf(acc[mi][ni][1]);
                pk.z = f2bf(acc[mi][ni][2]); pk.w = f2bf(acc[mi][ni][3]);
                *(ushort4*)&vt[((size_t)bb * DIM + d) * SEQ + ms] = pk;
            }
        }
    }
}

// ---------------- L2 normalize; outputs HEAD-MAJOR qn/kn [bh][n][16] ----------------
__global__ __launch_bounds__(256) void l2norm_split(const unsigned short* __restrict__ qkb,
                                                    unsigned short* __restrict__ qn,
                                                    unsigned short* __restrict__ kn)
{
    const int row = blockIdx.x;
    const int t = threadIdx.x;
    const unsigned short* p = qkb + (size_t)row * 512;
    float q = bf2f(p[t]);
    float k = bf2f(p[t + 256]);
    float sq = q * q, sk = k * k;
    #pragma unroll
    for (int off = 32; off > 0; off >>= 1) {
        sq += __shfl_down(sq, off);
        sk += __shfl_down(sk, off);
    }
    __shared__ float sh[8];
    const int wid = t >> 6;
    if ((t & 63) == 0) { sh[wid * 2] = sq; sh[wid * 2 + 1] = sk; }
    __syncthreads();
    sq = sh[0] + sh[2] + sh[4] + sh[6];
    sk = sh[1] + sh[3] + sh[5] + sh[7];
    const float rq = QSCALE / fmaxf(sqrtf(sq), 1e-6f);
    const float rk = 1.0f   / fmaxf(sqrtf(sk), 1e-6f);

    const int b = row >> 11, n = row & 2047;
    const int head = t >> 4, hs = t & 15;
    const size_t o = (((size_t)b * HEADS + head) * SEQ + n) * 16 + hs;
    qn[o] = f2bf(q * rq);
    kn[o] = f2bf(k * rk);
}

// ---------------- attn: 8-wave blocks, wave = (seg, qh, kh) ----------------
// 512 uniform pair-blocks {31-p, p} x 512 threads. Waves 0-3: heavy segment,
// 4-7: light. Each wave: ONE segment, 32 q rows (qh), 64 keys (kh) per 128-key
// tile -> o[2]=32 acc regs, single exp2/cvt chain. Light waves retire early,
// freeing SIMD slots for heavy waves (built-in tail boost). V dbuf staged by
// all 8 waves (2 gloads each), counted vmcnt(4); K coalesced head-major.

template<bool MASK>
__device__ __forceinline__ void segpv(const short8 ak0, const short8 ak1, const short8 bq,
                                      const unsigned short* Vs, int kb, int kh, int hi,
                                      int l31, int qg, f32x16 o[2], float& lp)
{
    const f32x16 z = {};
    short8 pa[4];

    const f32x16 s0 = __builtin_amdgcn_mfma_f32_32x32x16_bf16(ak0, bq, z, 0, 0, 0);
    {
        float p0[16];
        #pragma unroll
        for (int r = 0; r < 16; ++r) {
            float e = __builtin_exp2f(s0[r]);
            if (MASK) {
                const int kl = kb + (r & 3) + 8 * (r >> 2) + 4 * hi;
                e = (kl > qg) ? 0.0f : e;
            }
            p0[r] = e; lp += e;
        }
        #pragma unroll
        for (int g = 0; g < 2; ++g) {
            const int jj = 2 * g;
            unsigned a0, a1, b0, b1;
            asm("v_cvt_pk_bf16_f32 %0, %1, %2" : "=v"(a0) : "v"(p0[4*jj]),     "v"(p0[4*jj + 1]));
            asm("v_cvt_pk_bf16_f32 %0, %1, %2" : "=v"(b0) : "v"(p0[4*jj + 2]), "v"(p0[4*jj + 3]));
            asm("v_cvt_pk_bf16_f32 %0, %1, %2" : "=v"(a1) : "v"(p0[4*jj + 4]), "v"(p0[4*jj + 5]));
            asm("v_cvt_pk_bf16_f32 %0, %1, %2" : "=v"(b1) : "v"(p0[4*jj + 6]), "v"(p0[4*jj + 7]));
            const uint2v r0 = __builtin_amdgcn_permlane32_swap(a0, a1, false, false);
            const uint2v r1 = __builtin_amdgcn_permlane32_swap(b0, b1, false, false);
            union { short8 s; unsigned u[4]; } pu;
            pu.u[0] = r0[0]; pu.u[1] = r1[0]; pu.u[2] = r0[1]; pu.u[3] = r1[1];
            pa[g] = pu.s;
        }
    }
    const f32x16 s1 = __builtin_amdgcn_mfma_f32_32x32x16_bf16(ak1, bq, z, 0, 0, 0);
    {
        float p1[16];
        #pragma unroll
        for (int r = 0; r < 16; ++r) {
            float e = __builtin_exp2f(s1[r]);
            if (MASK) {
                const int kl = kb + 32 + (r & 3) + 8 * (r >> 2) + 4 * hi;
                e = (kl > qg) ? 0.0f : e;
            }
            p1[r] = e; lp += e;
        }
        #pragma unroll
        for (int g = 0; g < 2; ++g) {
            const int jj = 2 * g;
            unsigned a0, a1, b0, b1;
            asm("v_cvt_pk_bf16_f32 %0, %1, %2" : "=v"(a0) : "v"(p1[4*jj]),     "v"(p1[4*jj + 1]));
            asm("v_cvt_pk_bf16_f32 %0, %1, %2" : "=v"(b0) : "v"(p1[4*jj + 2]), "v"(p1[4*jj + 3]));
            asm("v_cvt_pk_bf16_f32 %0, %1, %2" : "=v"(a1) : "v"(p1[4*jj + 4]), "v"(p1[4*jj + 5]));
            asm("v_cvt_pk_bf16_f32 %0, %1, %2" : "=v"(b1) : "v"(p1[4*jj + 6]), "v"(p1[4*jj + 7]));
            const uint2v r0 = __builtin_amdgcn_permlane32_swap(a0, a1, false, false);
            const uint2v r1 = __builtin_amdgcn_permlane32_swap(b0, b1, false, false);
            union { short8 s; unsigned u[4]; } pu;
            pu.u[0] = r0[0]; pu.u[1] = r1[0]; pu.u[2] = r0[1]; pu.u[3] = r1[1];
            pa[2 + g] = pu.s;
        }
    }

    // PV: 4 key-groups x 2 dh-halves; V slot XOR (row&15) -> 2-way banks (free)
    #pragma unroll
    for (int g = 0; g < 4; ++g)
        #pragma unroll
        for (int half = 0; half < 2; ++half) {
            const int row = half * 32 + l31;
            const int slot = (8 * kh + 2 * g + hi) ^ (row & 15);
            const short8 bv = *(const short8*)&Vs[row * 128 + 8 * slot];
            o[half] = __builtin_amdgcn_mfma_f32_32x32x16_bf16(pa[g], bv, o[half], 0, 0, 0);
        }
}

__global__ __launch_bounds__(512, 4) void attn_w8(const unsigned short* __restrict__ qn,
                                                  const unsigned short* __restrict__ kn,
                                                  const unsigned short* __restrict__ vt,
                                                  float* __restrict__ out)
{
    const int L = blockIdx.x;            // 512; L%8 == bh%8 -> XCD-pinned
    const int bh = L & 31;
    const int p  = L >> 5;               // pair {31-p, p}
    const int h = bh & 15, b = bh >> 4;

    const int tid = threadIdx.x, w = tid >> 6, lane = tid & 63;
    const int seg = w >> 2, qh = (w >> 1) & 1, kh = w & 1;
    const int l31 = lane & 31, hi = lane >> 5;

    const int qt  = seg ? p : 31 - p;
    const int nts = (qt >> 1) + 1;       // this wave's active tiles
    const int nt0 = ((31 - p) >> 1) + 1; // loop trip count (heavy)
    const int band = qt * 64 + qh * 32;
    const int qg = band + l31;

    // V dbuf 2x16KB; epilogue overlay Os(2 seg x 16K) | Ls(2 seg x 512B)
    __shared__ __align__(16) unsigned char smem[33792];

    const unsigned short* qbh = qn + (size_t)bh * SEQ * 16;
    const unsigned short* kbh = kn + (size_t)bh * SEQ * 16;

    const short8 bq = *(const short8*)&qbh[qg * 16 + 8 * hi];

    f32x16 o[2] = {};
    float lp = 0.0f;

    // K window (kh): rows 64kh+l31, +32. Coalesced 2KB/wave (head-major).
    const unsigned short* kwin = kbh + (64 * kh + l31) * 16 + 8 * hi;
    short8 ak0 = *(const short8*)(kwin);
    short8 ak1 = *(const short8*)(kwin + 32 * 16);

    const int vsub = lane >> 4, vslot = lane & 15;

#define STAGEV(kt_, buf_) do {                                                                    \
        const int k0_ = (kt_) * 128;                                                              \
        _Pragma("unroll")                                                                         \
        for (int i = 0; i < 2; ++i) {                                                             \
            const int c = 2 * w + i;                                                              \
            const int dh = 4 * c + vsub;                                                          \
            const int so = 8 * (vslot ^ (dh & 15));                                               \
            __builtin_amdgcn_global_load_lds(                                                     \
                (GPTR)&vt[((size_t)b * DIM + h * DH + dh) * SEQ + k0_ + so],                      \
                (LPTR)(smem + (buf_) * 16384 + c * 1024), 16, 0, 0);                              \
        }                                                                                         \
    } while (0)

    STAGEV(0, 0);

    #pragma unroll 1
    for (int kt = 0; kt < nt0; ++kt) {
        short8 an0 = ak0, an1 = ak1;
        if (kt + 1 < nt0) {
            STAGEV(kt + 1, (kt + 1) & 1);
            an0 = *(const short8*)(kwin + (size_t)(kt + 1) * 128 * 16);
            an1 = *(const short8*)(kwin + (size_t)(kt + 1) * 128 * 16 + 32 * 16);
            asm volatile("s_waitcnt vmcnt(4)" ::: "memory");   // drain tile kt only
        } else {
            asm volatile("s_waitcnt vmcnt(0)" ::: "memory");
        }
        __builtin_amdgcn_sched_barrier(0);
        __builtin_amdgcn_s_barrier();        // stage(kt) visible to all waves

        if (kt < nts) {
            const unsigned short* Vs = (const unsigned short*)(smem + (kt & 1) * 16384);
            const int kb = kt * 128 + 64 * kh;
            __builtin_amdgcn_s_setprio(1);
            if (kt < nts - 1) {
                segpv<false>(ak0, ak1, bq, Vs, kb, kh, hi, l31, qg, o, lp);
            } else if (kb <= band + 31) {
                if (kb + 63 <= band) segpv<false>(ak0, ak1, bq, Vs, kb, kh, hi, l31, qg, o, lp);
                else                 segpv<true >(ak0, ak1, bq, Vs, kb, kh, hi, l31, qg, o, lp);
            }
            __builtin_amdgcn_s_setprio(0);
        }

        ak0 = an0; ak1 = an1;
        __builtin_amdgcn_s_barrier();        // all waves done reading buf kt
    }
#undef STAGEV

    // ---- epilogue: per-seg 2-way kh merge, normalize, store ----
    lp += __shfl_xor(lp, 32);                // fold hi halves: per-q totals

    __syncthreads();                         // V dbuf dead; reuse smem
    float* Os = (float*)(smem + seg * 16384);      // [2 qh][32 q][64 lane]
    float* Ls = (float*)(smem + 32768 + seg * 512);// [2 qh][64 lane]

    if (kh == 1) {
        #pragma unroll
        for (int half = 0; half < 2; ++half)
            #pragma unroll
            for (int r = 0; r < 16; ++r) {
                const int q = (r & 3) + 8 * (r >> 2) + 4 * hi;
                Os[(qh * 32 + q) * 64 + half * 32 + l31] = o[half][r];
            }
        Ls[qh * 64 + lane] = lp;
    }
    __syncthreads();
    if (kh == 0) {
        const float lt = lp + Ls[qh * 64 + lane];
        const float inv = 1.0f / fmaxf(lt, 1e-6f);
        #pragma unroll
        for (int r = 0; r < 16; ++r) {
            const int q = (r & 3) + 8 * (r >> 2) + 4 * hi;
            const float iv = __shfl(inv, q);
            #pragma unroll
            for (int half = 0; half < 2; ++half) {
                const float v = (o[half][r] + Os[(qh * 32 + q) * 64 + half * 32 + l31]) * iv;
                __builtin_nontemporal_store(v,
                    &out[((size_t)b * SEQ + band + q) * DIM + h * DH + half * 32 + l31]);
            }
        }
    }
}

extern "C" void kernel_launch(void* const* d_in, const int* in_sizes, int n_in,
                              void* d_out, int out_size, void* d_ws, size_t ws_size,
                              hipStream_t stream)
{
    const float* x   = (const float*)d_in[0];
    // d_in[1] = mask (causal, analytic)
    const float* Wqk = (const float*)d_in[2];
    const float* Wv  = (const float*)d_in[3];
    float* out = (float*)d_out;

    // workspace: xb 8MB | qkb 4MB | vt 8MB | wcat 3MB ; qn/kn (head-major, 2MB each)
    // overlay xb after the GEMM (xb dead by then)
    unsigned short* xb   = (unsigned short*)d_ws;
    unsigned short* qkb  = xb  + (size_t)MROWS * DIM;
    unsigned short* vt   = qkb + (size_t)MROWS * 512;
    unsigned short* wcat = vt  + (size_t)BATCH * DIM * SEQ;
    unsigned short* qn = xb;                               // [32 bh][2048][16]
    unsigned short* kn = xb + (size_t)32 * SEQ * 16;

    conv3<<<5632, 256, 0, stream>>>(x, Wqk, Wv, xb, wcat);
    gemm_mfma<<<768, 256, 0, stream>>>(xb, wcat, qkb, vt);
    l2norm_split<<<MROWS, 256, 0, stream>>>(qkb, qn, kn);
    attn_w8<<<512, 512, 0, stream>>>(qn, kn, vt, out);
}